// Round 10
// baseline (68.830 us; speedup 1.0000x reference)
//
#include <hip/hip_runtime.h>

#define BATCH 8
#define NROW  2048
#define NF    64
#define JSPLIT 4
#define JPB   (NROW / JSPLIT)               // 512 k per block (split path)
#define CHUNK 32
#define TOT   ((size_t)BATCH * NROW * NF)   // 1048576

typedef float  f32x4  __attribute__((ext_vector_type(4)));
typedef __bf16 bf16x8 __attribute__((ext_vector_type(8)));
typedef unsigned short u16x8 __attribute__((ext_vector_type(8)));

union frag_cast { u16x8 u; bf16x8 b; };

#define AS1 __attribute__((address_space(1)))
#define AS3 __attribute__((address_space(3)))

__device__ __forceinline__ void gld16u(const unsigned short* g, unsigned short* l) {
  __builtin_amdgcn_global_load_lds((const AS1 void*)g, (AS3 void*)l, 16, 0, 0);
}
__device__ __forceinline__ float ubits(unsigned u) {
  union { unsigned u; float f; } c; c.u = u; return c.f;
}
__device__ __forceinline__ unsigned fbits(float f) {
  union { float f; unsigned u; } c; c.f = f; return c.u;
}

// ---- pass 1: transpose x, split into 3 bf16 levels: xs[lvl][b][f][j] ----
__global__ __launch_bounds__(256, 4)
void prep_x(const float* __restrict__ xg, unsigned short* __restrict__ xs) {
  __shared__ float t[64][65];
  const int b  = blockIdx.y;
  const int j0 = blockIdx.x * 64;
  const int l  = threadIdx.x & 63;
  const int g  = threadIdx.x >> 6;
  const float* src = xg + ((size_t)b * NROW + j0) * NF;
#pragma unroll
  for (int k = 0; k < 16; ++k) {
    const int j = g * 16 + k;
    t[j][l] = src[(size_t)j * NF + l];
  }
  __syncthreads();
#pragma unroll
  for (int k = 0; k < 16; ++k) {
    const int f = g * 16 + k;
    const float v = t[l][f];
    const unsigned u0 = fbits(v);
    const float f0 = ubits(u0 & 0xFFFF0000u);
    const float r  = v - f0;
    const unsigned u1 = fbits(r);
    const float f1 = ubits(u1 & 0xFFFF0000u);
    const float r2 = r - f1;
    const unsigned u2 = fbits(r2);
    const unsigned short s2 =
        (unsigned short)((u2 + 0x7FFFu + ((u2 >> 16) & 1u)) >> 16);
    const size_t o = ((size_t)b * NF + f) * NROW + j0 + l;
    xs[o]           = (unsigned short)(u0 >> 16);
    xs[o + TOT]     = (unsigned short)(u1 >> 16);
    xs[o + 2 * TOT] = s2;
  }
}

// split 8 f32 -> 3 bf16 fragments (proven r5-r9)
__device__ __forceinline__ void split8(const f32x4 q0, const f32x4 q1,
                                       frag_cast* Af) {
  float av[8];
  *(f32x4*)&av[0] = q0;
  *(f32x4*)&av[4] = q1;
  u16x8 h0, h1, h2;
#pragma unroll
  for (int e = 0; e < 8; ++e) {
    const unsigned u0 = fbits(av[e]);
    const float f0 = ubits(u0 & 0xFFFF0000u);
    const float r  = av[e] - f0;
    const unsigned u1 = fbits(r);
    const float f1 = ubits(u1 & 0xFFFF0000u);
    const float r2 = r - f1;
    const unsigned u2 = fbits(r2);
    h0[e] = (unsigned short)(u0 >> 16);
    h1[e] = (unsigned short)(u1 >> 16);
    h2[e] = (unsigned short)((u2 + 0x7FFFu + ((u2 >> 16) & 1u)) >> 16);
  }
  Af[0].u = h0; Af[1].u = h1; Af[2].u = h2;
}

// ---- pass 2: split-bf16 MFMA GEMM; A global->reg frags, B via gld_lds ----
// Grid 1024, block 64r x 64c x K=512. Waves 2x2: wave = 32r x 32c = four
// 16x16x32 tiles (4 independent MFMA chains). A-fragments load straight
// from row-major a with perfect coalescing (16 full lines per wave-instr),
// ping-pong prefetched one chunk ahead (drained by the barrier's vmcnt).
// LDS: B only, 2 x 12KB, XOR-swizzled via pre-swizzled source (r7 scheme).
// b = flat&7 -> each XCD owns one batch (xs slice L2-resident).
template <bool DIRECT>
__global__ __launch_bounds__(256, 3)
void gemm_mfma(const float* __restrict__ ag, const unsigned short* __restrict__ xs,
               float* __restrict__ outg, float* __restrict__ wp) {
  __shared__ __align__(16) unsigned short sB[2][3 * 64 * CHUNK];   // 2 x 12KB

  const int tid   = threadIdx.x;
  const int ln    = tid & 63;
  const int wv    = tid >> 6;
  const int ln15  = ln & 15;          // A row / B col / D col (in 16-tile)
  const int g     = ln >> 4;          // k-group / D row-group
  const int rhalf = wv & 1;
  const int chalf = wv >> 1;
  const int bkey  = (ln15 >> 1) & 3;

  const int flat = blockIdx.x;
  const int b    = flat & 7;                      // batch <-> XCD
  const int bx   = (flat >> 3) & 31;
  const int z    = DIRECT ? 0 : (flat >> 8);
  const int i0   = bx * 64;
  const int jb   = z * JPB;
  const int nch  = (DIRECT ? NROW : JPB) / CHUNK;   // 64 or 16 (even)

  const float* aA =
      ag + ((size_t)b * NROW + i0 + rhalf * 32 + ln15) * NROW + jb + g * 8;
  const unsigned short* xB = xs + (size_t)b * NF * NROW;

  // stage B chunk at k-offset j0 (linear LDS dest, inverse-swizzled source)
  auto stageB = [&](int buf, int j0) {
#pragma unroll
    for (int lvl = 0; lvl < 3; ++lvl) {
      const int n = tid >> 2;
      const int q = (tid & 3) ^ ((n >> 1) & 3);
      gld16u(xB + (size_t)lvl * TOT + (size_t)n * NROW + j0 + q * 8,
             &sB[buf][0] + (lvl * 256 + wv * 64) * 8);
    }
  };
  // load A fragments for chunk t into regs (2 row-tiles x 2 f32x4)
  auto loadA = [&](int t, f32x4 (&A)[2][2]) {
#pragma unroll
    for (int rt = 0; rt < 2; ++rt) {
      const float* p = aA + (size_t)rt * 16 * NROW + t * CHUNK;
      A[rt][0] = *(const f32x4*)(p);
      A[rt][1] = *(const f32x4*)(p + 4);
    }
  };

  double macc[2][2][4];
#pragma unroll
  for (int i = 0; i < 2; ++i)
#pragma unroll
    for (int j = 0; j < 2; ++j)
#pragma unroll
      for (int r = 0; r < 4; ++r) macc[i][j][r] = 0.0;

  constexpr int AI[6] = {2, 0, 1, 1, 0, 0};
  constexpr int BI[6] = {0, 2, 1, 0, 1, 0};

  f32x4 Aa[2][2], Ab[2][2];
  loadA(0, Aa);
  stageB(0, jb);

  auto body = [&](int t, f32x4 (&Ac)[2][2], f32x4 (&An)[2][2]) {
    __syncthreads();                 // drains stage(t) AND A-prefetch(t)
    if (t + 1 < nch) {
      stageB((t + 1) & 1, jb + (t + 1) * CHUNK);
      loadA(t + 1, An);
    }
    const unsigned short* sBb = &sB[t & 1][0];

    frag_cast Bv[2][3];
#pragma unroll
    for (int ct = 0; ct < 2; ++ct) {
      const int ncol = chalf * 32 + ct * 16 + ln15;
      const int bq   = g ^ bkey;
#pragma unroll
      for (int lvl = 0; lvl < 3; ++lvl)
        Bv[ct][lvl].u = *(const u16x8*)(sBb + lvl * 2048 + ncol * 32 + bq * 8);
    }
    frag_cast Af[2][3];
#pragma unroll
    for (int rt = 0; rt < 2; ++rt) split8(Ac[rt][0], Ac[rt][1], Af[rt]);

    f32x4 c[2][2];
#pragma unroll
    for (int rt = 0; rt < 2; ++rt)
#pragma unroll
      for (int ct = 0; ct < 2; ++ct) c[rt][ct] = (f32x4){0.f, 0.f, 0.f, 0.f};

#pragma unroll
    for (int term = 0; term < 6; ++term)
#pragma unroll
      for (int rt = 0; rt < 2; ++rt)
#pragma unroll
        for (int ct = 0; ct < 2; ++ct)
          c[rt][ct] = __builtin_amdgcn_mfma_f32_16x16x32_bf16(
              Af[rt][AI[term]].b, Bv[ct][BI[term]].b, c[rt][ct], 0, 0, 0);

#pragma unroll
    for (int rt = 0; rt < 2; ++rt)
#pragma unroll
      for (int ct = 0; ct < 2; ++ct) {
        macc[rt][ct][0] += (double)c[rt][ct].x;
        macc[rt][ct][1] += (double)c[rt][ct].y;
        macc[rt][ct][2] += (double)c[rt][ct].z;
        macc[rt][ct][3] += (double)c[rt][ct].w;
      }
  };

#pragma unroll 1
  for (int t = 0; t < nch; t += 2) {
    body(t, Aa, Ab);
    body(t + 1, Ab, Aa);
  }

  // epilogue: D row = g*4 + r (within 16-tile), col = ln15
  if (DIRECT) {
#pragma unroll
    for (int rt = 0; rt < 2; ++rt)
#pragma unroll
      for (int ct = 0; ct < 2; ++ct)
#pragma unroll
        for (int r = 0; r < 4; ++r)
          outg[((size_t)b * NROW + i0 + rhalf * 32 + rt * 16 + g * 4 + r) * NF +
               chalf * 32 + ct * 16 + ln15] =
              (macc[rt][ct][r] > 0.5) ? 1.0f : 0.0f;
  } else {
    float* wb = wp + (size_t)z * TOT;
#pragma unroll
    for (int rt = 0; rt < 2; ++rt)
#pragma unroll
      for (int ct = 0; ct < 2; ++ct)
#pragma unroll
        for (int r = 0; r < 4; ++r)
          wb[((size_t)b * NROW + i0 + rhalf * 32 + rt * 16 + g * 4 + r) * NF +
             chalf * 32 + ct * 16 + ln15] = (float)macc[rt][ct][r];
  }
}

// ---- pass 3: reduce JSPLIT partials in f64, threshold ----
__global__ __launch_bounds__(256)
void combine_thresh(const float* __restrict__ wsv, float* __restrict__ outg) {
  const size_t e = ((size_t)blockIdx.x * 256 + threadIdx.x) * 4;
  f32x4 p0 = *(const f32x4*)(wsv + e);
  f32x4 p1 = *(const f32x4*)(wsv + e + TOT);
  f32x4 p2 = *(const f32x4*)(wsv + e + 2 * TOT);
  f32x4 p3 = *(const f32x4*)(wsv + e + 3 * TOT);
  f32x4 o;
  o.x = (((double)p0.x + p1.x + p2.x + p3.x) > 0.5) ? 1.0f : 0.0f;
  o.y = (((double)p0.y + p1.y + p2.y + p3.y) > 0.5) ? 1.0f : 0.0f;
  o.z = (((double)p0.z + p1.z + p2.z + p3.z) > 0.5) ? 1.0f : 0.0f;
  o.w = (((double)p0.w + p1.w + p2.w + p3.w) > 0.5) ? 1.0f : 0.0f;
  *(f32x4*)(outg + e) = o;
}

extern "C" void kernel_launch(void* const* d_in, const int* in_sizes, int n_in,
                              void* d_out, int out_size, void* d_ws, size_t ws_size,
                              hipStream_t stream) {
  const float* x = (const float*)d_in[0];
  const float* a = (const float*)d_in[1];
  float* out = (float*)d_out;
  unsigned short* xs = (unsigned short*)d_ws;                 // 6 MB
  float* wp = (float*)((char*)d_ws + 3 * TOT * sizeof(unsigned short));

  prep_x<<<dim3(NROW / 64, BATCH), dim3(256), 0, stream>>>(x, xs);

  const size_t need = 3 * TOT * sizeof(unsigned short)
                    + (size_t)JSPLIT * TOT * sizeof(float);   // 22 MB
  if (ws_size >= need) {
    gemm_mfma<false><<<dim3(JSPLIT * BATCH * (NROW / 64)), dim3(256), 0, stream>>>(
        a, xs, out, wp);
    combine_thresh<<<dim3((unsigned)(TOT / 1024)), dim3(256), 0, stream>>>(wp, out);
  } else {
    gemm_mfma<true><<<dim3(BATCH * (NROW / 64)), dim3(256), 0, stream>>>(
        a, xs, out, nullptr);
  }
}

// Round 11
// 51.483 us; speedup vs baseline: 1.3369x; 1.3369x over previous
//
#include <hip/hip_runtime.h>

#define BATCH 8
#define NROW  2048
#define NF    64
#define JSPLIT 4
#define JPB   (NROW / JSPLIT)               // 512 k per block (split path)
#define CHUNK 32
#define TOT   ((size_t)BATCH * NROW * NF)   // 1048576

typedef float  f32x4  __attribute__((ext_vector_type(4)));
typedef __bf16 bf16x8 __attribute__((ext_vector_type(8)));
typedef unsigned short u16x8 __attribute__((ext_vector_type(8)));

union frag_cast { u16x8 u; bf16x8 b; };

#define AS1 __attribute__((address_space(1)))
#define AS3 __attribute__((address_space(3)))

__device__ __forceinline__ void gld16f(const float* g, float* l) {
  __builtin_amdgcn_global_load_lds((const AS1 void*)g, (AS3 void*)l, 16, 0, 0);
}
__device__ __forceinline__ void gld16u(const unsigned short* g, unsigned short* l) {
  __builtin_amdgcn_global_load_lds((const AS1 void*)g, (AS3 void*)l, 16, 0, 0);
}
__device__ __forceinline__ float ubits(unsigned u) {
  union { unsigned u; float f; } c; c.u = u; return c.f;
}
__device__ __forceinline__ unsigned fbits(float f) {
  union { float f; unsigned u; } c; c.f = f; return c.u;
}

// ---- pass 1: transpose x, split into 3 bf16 levels: xs[lvl][b][f][j] ----
__global__ __launch_bounds__(256, 4)
void prep_x(const float* __restrict__ xg, unsigned short* __restrict__ xs) {
  __shared__ float t[64][65];
  const int b  = blockIdx.y;
  const int j0 = blockIdx.x * 64;
  const int l  = threadIdx.x & 63;
  const int g  = threadIdx.x >> 6;
  const float* src = xg + ((size_t)b * NROW + j0) * NF;
#pragma unroll
  for (int k = 0; k < 16; ++k) {
    const int j = g * 16 + k;
    t[j][l] = src[(size_t)j * NF + l];
  }
  __syncthreads();
#pragma unroll
  for (int k = 0; k < 16; ++k) {
    const int f = g * 16 + k;
    const float v = t[l][f];
    const unsigned u0 = fbits(v);
    const float f0 = ubits(u0 & 0xFFFF0000u);
    const float r  = v - f0;
    const unsigned u1 = fbits(r);
    const float f1 = ubits(u1 & 0xFFFF0000u);
    const float r2 = r - f1;
    const unsigned u2 = fbits(r2);
    const unsigned short s2 =
        (unsigned short)((u2 + 0x7FFFu + ((u2 >> 16) & 1u)) >> 16);
    const size_t o = ((size_t)b * NF + f) * NROW + j0 + l;
    xs[o]           = (unsigned short)(u0 >> 16);
    xs[o + TOT]     = (unsigned short)(u1 >> 16);
    xs[o + 2 * TOT] = s2;
  }
}

// split 8 f32 -> 3 bf16 fragments (proven r5-r10)
__device__ __forceinline__ void split8(const f32x4 q0, const f32x4 q1,
                                       frag_cast* Af) {
  float av[8];
  *(f32x4*)&av[0] = q0;
  *(f32x4*)&av[4] = q1;
  u16x8 h0, h1, h2;
#pragma unroll
  for (int e = 0; e < 8; ++e) {
    const unsigned u0 = fbits(av[e]);
    const float f0 = ubits(u0 & 0xFFFF0000u);
    const float r  = av[e] - f0;
    const unsigned u1 = fbits(r);
    const float f1 = ubits(u1 & 0xFFFF0000u);
    const float r2 = r - f1;
    const unsigned u2 = fbits(r2);
    h0[e] = (unsigned short)(u0 >> 16);
    h1[e] = (unsigned short)(u1 >> 16);
    h2[e] = (unsigned short)((u2 + 0x7FFFu + ((u2 >> 16) & 1u)) >> 16);
  }
  Af[0].u = h0; Af[1].u = h1; Af[2].u = h2;
}

// ---- pass 2: split-bf16 MFMA GEMM, A+B LDS-staged (r7 skeleton),
//      wave = 32x32 (2x2 of 16x16 tiles): LDS reads 10/wave-chunk vs r7's 14.
// Grid 1024, 4 blocks/CU. LDS: A 8KB f32 + B 12KB bf16x3, dbuf = 40KB.
// XOR-swizzle via pre-swizzled global source (linear gld_lds dest, same XOR
// on read; verified uniform 8 lanes/bank = b128 minimum). b = flat&7 matches
// HW XCD round-robin -> each XCD re-reads only its own 768KB xs slice.
template <bool DIRECT>
__global__ __launch_bounds__(256, 4)
void gemm_mfma(const float* __restrict__ ag, const unsigned short* __restrict__ xs,
               float* __restrict__ outg, float* __restrict__ wp) {
  __shared__ __align__(16) float sA[2][64 * CHUNK];                 // 2 x 8KB
  __shared__ __align__(16) unsigned short sB[2][3 * 64 * CHUNK];    // 2 x 12KB

  const int tid   = threadIdx.x;
  const int ln    = tid & 63;
  const int wv    = tid >> 6;
  const int ln15  = ln & 15;          // A row / B col / D col (within 16-tile)
  const int g     = ln >> 4;          // k-group / D row-group
  const int rhalf = wv & 1;           // wave row half (32 rows)
  const int chalf = wv >> 1;          // wave col half (32 cols)
  const int akey  = ln15 & 7;
  const int bkey  = (ln15 >> 1) & 3;

  const int flat = blockIdx.x;
  const int b    = flat & 7;                      // batch <-> XCD (HW rr)
  const int bx   = (flat >> 3) & 31;
  const int z    = DIRECT ? 0 : (flat >> 8);
  const int i0   = bx * 64;
  const int jb   = z * JPB;
  const int nch  = (DIRECT ? NROW : JPB) / CHUNK;   // 64 or 16

  const float* aB = ag + ((size_t)b * NROW + i0) * NROW;
  const unsigned short* xB = xs + (size_t)b * NF * NROW;

  // stage chunk at k-offset j0 (linear LDS dest, inverse-swizzled source)
  auto stage = [&](int buf, int j0) {
#pragma unroll
    for (int i = 0; i < 2; ++i) {            // A: 512 x 16B slots
      const int s   = i * 256 + tid;
      const int row = s >> 3;
      const int q   = (s & 7) ^ (row & 7);
      gld16f(aB + (size_t)row * NROW + j0 + q * 4,
             &sA[buf][0] + (i * 256 + wv * 64) * 4);
    }
#pragma unroll
    for (int lvl = 0; lvl < 3; ++lvl) {      // B: 3 x 256 x 16B slots
      const int n = tid >> 2;
      const int q = (tid & 3) ^ ((n >> 1) & 3);
      gld16u(xB + (size_t)lvl * TOT + (size_t)n * NROW + j0 + q * 8,
             &sB[buf][0] + (lvl * 256 + wv * 64) * 8);
    }
  };

  double macc[2][2][4];
#pragma unroll
  for (int i = 0; i < 2; ++i)
#pragma unroll
    for (int j = 0; j < 2; ++j)
#pragma unroll
      for (int r = 0; r < 4; ++r) macc[i][j][r] = 0.0;

  constexpr int AI[6] = {2, 0, 1, 1, 0, 0};
  constexpr int BI[6] = {0, 2, 1, 0, 1, 0};

  stage(0, jb);

#pragma unroll 1
  for (int t = 0; t < nch; ++t) {
    __syncthreads();                  // drains stage(t); buf^1 free
    if (t + 1 < nch) stage((t + 1) & 1, jb + (t + 1) * CHUNK);

    const float* sAb = &sA[t & 1][0];
    const unsigned short* sBb = &sB[t & 1][0];

    // A fragments for both row-tiles (row = rhalf*32 + rt*16 + ln15)
    frag_cast Af[2][3];
#pragma unroll
    for (int rt = 0; rt < 2; ++rt) {
      const int rowL = rhalf * 32 + rt * 16 + ln15;
      const f32x4 q0 = *(const f32x4*)(sAb + rowL * 32 + (((2 * g)     ^ akey) << 2));
      const f32x4 q1 = *(const f32x4*)(sAb + rowL * 32 + (((2 * g + 1) ^ akey) << 2));
      split8(q0, q1, Af[rt]);
    }

    f32x4 c[2][2];
#pragma unroll
    for (int rt = 0; rt < 2; ++rt)
#pragma unroll
      for (int ct = 0; ct < 2; ++ct) c[rt][ct] = (f32x4){0.f, 0.f, 0.f, 0.f};

    // per col-tile: read 3 B levels, run 12 MFMAs (2 interleaved chains)
#pragma unroll
    for (int ct = 0; ct < 2; ++ct) {
      const int ncol = chalf * 32 + ct * 16 + ln15;
      const int bq   = g ^ bkey;
      frag_cast Bv[3];
#pragma unroll
      for (int lvl = 0; lvl < 3; ++lvl)
        Bv[lvl].u = *(const u16x8*)(sBb + lvl * 2048 + ncol * 32 + bq * 8);
#pragma unroll
      for (int term = 0; term < 6; ++term)
#pragma unroll
        for (int rt = 0; rt < 2; ++rt)
          c[rt][ct] = __builtin_amdgcn_mfma_f32_16x16x32_bf16(
              Af[rt][AI[term]].b, Bv[BI[term]].b, c[rt][ct], 0, 0, 0);
    }

#pragma unroll
    for (int rt = 0; rt < 2; ++rt)
#pragma unroll
      for (int ct = 0; ct < 2; ++ct) {
        macc[rt][ct][0] += (double)c[rt][ct].x;
        macc[rt][ct][1] += (double)c[rt][ct].y;
        macc[rt][ct][2] += (double)c[rt][ct].z;
        macc[rt][ct][3] += (double)c[rt][ct].w;
      }
  }

  // epilogue: D row = g*4 + r (within 16-tile), col = ln15 (verified r5-r10)
  if (DIRECT) {
#pragma unroll
    for (int rt = 0; rt < 2; ++rt)
#pragma unroll
      for (int ct = 0; ct < 2; ++ct)
#pragma unroll
        for (int r = 0; r < 4; ++r)
          outg[((size_t)b * NROW + i0 + rhalf * 32 + rt * 16 + g * 4 + r) * NF +
               chalf * 32 + ct * 16 + ln15] =
              (macc[rt][ct][r] > 0.5) ? 1.0f : 0.0f;
  } else {
    float* wb = wp + (size_t)z * TOT;
#pragma unroll
    for (int rt = 0; rt < 2; ++rt)
#pragma unroll
      for (int ct = 0; ct < 2; ++ct)
#pragma unroll
        for (int r = 0; r < 4; ++r)
          wb[((size_t)b * NROW + i0 + rhalf * 32 + rt * 16 + g * 4 + r) * NF +
             chalf * 32 + ct * 16 + ln15] = (float)macc[rt][ct][r];
  }
}

// ---- pass 3: reduce JSPLIT partials in f64, threshold ----
__global__ __launch_bounds__(256)
void combine_thresh(const float* __restrict__ wsv, float* __restrict__ outg) {
  const size_t e = ((size_t)blockIdx.x * 256 + threadIdx.x) * 4;
  f32x4 p0 = *(const f32x4*)(wsv + e);
  f32x4 p1 = *(const f32x4*)(wsv + e + TOT);
  f32x4 p2 = *(const f32x4*)(wsv + e + 2 * TOT);
  f32x4 p3 = *(const f32x4*)(wsv + e + 3 * TOT);
  f32x4 o;
  o.x = (((double)p0.x + p1.x + p2.x + p3.x) > 0.5) ? 1.0f : 0.0f;
  o.y = (((double)p0.y + p1.y + p2.y + p3.y) > 0.5) ? 1.0f : 0.0f;
  o.z = (((double)p0.z + p1.z + p2.z + p3.z) > 0.5) ? 1.0f : 0.0f;
  o.w = (((double)p0.w + p1.w + p2.w + p3.w) > 0.5) ? 1.0f : 0.0f;
  *(f32x4*)(outg + e) = o;
}

extern "C" void kernel_launch(void* const* d_in, const int* in_sizes, int n_in,
                              void* d_out, int out_size, void* d_ws, size_t ws_size,
                              hipStream_t stream) {
  const float* x = (const float*)d_in[0];
  const float* a = (const float*)d_in[1];
  float* out = (float*)d_out;
  unsigned short* xs = (unsigned short*)d_ws;                 // 6 MB
  float* wp = (float*)((char*)d_ws + 3 * TOT * sizeof(unsigned short));

  prep_x<<<dim3(NROW / 64, BATCH), dim3(256), 0, stream>>>(x, xs);

  const size_t need = 3 * TOT * sizeof(unsigned short)
                    + (size_t)JSPLIT * TOT * sizeof(float);   // 22 MB
  if (ws_size >= need) {
    gemm_mfma<false><<<dim3(JSPLIT * BATCH * (NROW / 64)), dim3(256), 0, stream>>>(
        a, xs, out, wp);
    combine_thresh<<<dim3((unsigned)(TOT / 1024)), dim3(256), 0, stream>>>(wp, out);
  } else {
    gemm_mfma<true><<<dim3(BATCH * (NROW / 64)), dim3(256), 0, stream>>>(
        a, xs, out, nullptr);
  }
}

// Round 12
// 47.681 us; speedup vs baseline: 1.4435x; 1.0797x over previous
//
#include <hip/hip_runtime.h>

#define BATCH 8
#define NROW  2048
#define NF    64
#define JSPLIT 4
#define JPB   (NROW / JSPLIT)               // 512 k per block (split path)
#define CHUNK 32
#define TOT   ((size_t)BATCH * NROW * NF)   // 1048576

typedef float  f32x4  __attribute__((ext_vector_type(4)));
typedef __bf16 bf16x8 __attribute__((ext_vector_type(8)));
typedef unsigned short u16x8 __attribute__((ext_vector_type(8)));

union frag_cast { u16x8 u; bf16x8 b; };

#define AS1 __attribute__((address_space(1)))
#define AS3 __attribute__((address_space(3)))

__device__ __forceinline__ void gld16u(const unsigned short* g, unsigned short* l) {
  __builtin_amdgcn_global_load_lds((const AS1 void*)g, (AS3 void*)l, 16, 0, 0);
}
__device__ __forceinline__ float ubits(unsigned u) {
  union { unsigned u; float f; } c; c.u = u; return c.f;
}
__device__ __forceinline__ unsigned fbits(float f) {
  union { float f; unsigned u; } c; c.f = f; return c.u;
}

// ---- pass 1: transpose x, split into 3 bf16 levels: xs[lvl][b][f][j] ----
__global__ __launch_bounds__(256, 4)
void prep_x(const float* __restrict__ xg, unsigned short* __restrict__ xs) {
  __shared__ float t[64][65];
  const int b  = blockIdx.y;
  const int j0 = blockIdx.x * 64;
  const int l  = threadIdx.x & 63;
  const int g  = threadIdx.x >> 6;
  const float* src = xg + ((size_t)b * NROW + j0) * NF;
#pragma unroll
  for (int k = 0; k < 16; ++k) {
    const int j = g * 16 + k;
    t[j][l] = src[(size_t)j * NF + l];
  }
  __syncthreads();
#pragma unroll
  for (int k = 0; k < 16; ++k) {
    const int f = g * 16 + k;
    const float v = t[l][f];
    const unsigned u0 = fbits(v);
    const float f0 = ubits(u0 & 0xFFFF0000u);
    const float r  = v - f0;
    const unsigned u1 = fbits(r);
    const float f1 = ubits(u1 & 0xFFFF0000u);
    const float r2 = r - f1;
    const unsigned u2 = fbits(r2);
    const unsigned short s2 =
        (unsigned short)((u2 + 0x7FFFu + ((u2 >> 16) & 1u)) >> 16);
    const size_t o = ((size_t)b * NF + f) * NROW + j0 + l;
    xs[o]           = (unsigned short)(u0 >> 16);
    xs[o + TOT]     = (unsigned short)(u1 >> 16);
    xs[o + 2 * TOT] = s2;
  }
}

// split 8 f32 -> 3 bf16 fragments (proven r5-r11)
__device__ __forceinline__ void split8(const f32x4 q0, const f32x4 q1,
                                       frag_cast* Af) {
  float av[8];
  *(f32x4*)&av[0] = q0;
  *(f32x4*)&av[4] = q1;
  u16x8 h0, h1, h2;
#pragma unroll
  for (int e = 0; e < 8; ++e) {
    const unsigned u0 = fbits(av[e]);
    const float f0 = ubits(u0 & 0xFFFF0000u);
    const float r  = av[e] - f0;
    const unsigned u1 = fbits(r);
    const float f1 = ubits(u1 & 0xFFFF0000u);
    const float r2 = r - f1;
    const unsigned u2 = fbits(r2);
    h0[e] = (unsigned short)(u0 >> 16);
    h1[e] = (unsigned short)(u1 >> 16);
    h2[e] = (unsigned short)((u2 + 0x7FFFu + ((u2 >> 16) & 1u)) >> 16);
  }
  Af[0].u = h0; Af[1].u = h1; Af[2].u = h2;
}

// ---- pass 2: split-bf16 MFMA GEMM, depth-2 pipeline (r7 geometry) ----
// Block: 4 waves, wave = 16 rows x 64 cols (4 n-tiles, 4 independent MFMA
// chains). A: global->reg fragments (natively coalesced), prefetched TWO
// chunks ahead. B: LDS dbuf 2x12KB via gld_lds, pre-swizzled source.
// Barrier = counted `s_waitcnt vmcnt(2)` + raw s_barrier: drains only B(t);
// A(t+1) (register-private) and B(t+1) (issued post-barrier into the free
// buffer) stay in flight. b = flat&7 == XCD -> xs slice L2-resident.
template <bool DIRECT>
__global__ __launch_bounds__(256, 4)
void gemm_mfma(const float* __restrict__ ag, const unsigned short* __restrict__ xs,
               float* __restrict__ outg, float* __restrict__ wp) {
  __shared__ __align__(16) unsigned short sB[2][3 * 64 * CHUNK];   // 2 x 12KB

  const int tid  = threadIdx.x;
  const int ln   = tid & 63;
  const int wv   = tid >> 6;
  const int ln15 = ln & 15;          // A row / B col / D col (in 16-tile)
  const int g    = ln >> 4;          // k-group / D row-group
  const int bkey = (ln15 >> 1) & 3;

  const int flat = blockIdx.x;
  const int b    = flat & 7;                      // batch == XCD (r7-equiv)
  const int rr   = flat >> 3;
  const int bx   = rr & 31;
  const int z    = DIRECT ? 0 : ((rr >> 5) & 3);
  const int i0   = bx * 64;
  const int jb   = z * JPB;
  const int nch  = (DIRECT ? NROW : JPB) / CHUNK;   // 64 or 16 (even)

  const float* aA =
      ag + ((size_t)b * NROW + i0 + wv * 16 + ln15) * NROW + jb + g * 8;
  const unsigned short* xB = xs + (size_t)b * NF * NROW;

  // stage B chunk (3 gld_lds per thread; linear dest, inverse-swizzled src)
  auto stageB = [&](int buf, int j0) {
#pragma unroll
    for (int lvl = 0; lvl < 3; ++lvl) {
      const int n = tid >> 2;
      const int q = (tid & 3) ^ ((n >> 1) & 3);
      gld16u(xB + (size_t)lvl * TOT + (size_t)n * NROW + j0 + q * 8,
             &sB[buf][0] + (lvl * 256 + wv * 64) * 8);
    }
  };

  double macc[4][4];
#pragma unroll
  for (int i = 0; i < 4; ++i)
#pragma unroll
    for (int j = 0; j < 4; ++j) macc[i][j] = 0.0;

  constexpr int AI[6] = {2, 0, 1, 1, 0, 0};
  constexpr int BI[6] = {0, 2, 1, 0, 1, 0};

  // prologue: B(0) staged; A(0), A(1) in regs
  stageB(0, jb);
  f32x4 Aa0 = *(const f32x4*)(aA);
  f32x4 Aa1 = *(const f32x4*)(aA + 4);
  f32x4 Ab0 = *(const f32x4*)(aA + CHUNK);
  f32x4 Ab1 = *(const f32x4*)(aA + CHUNK + 4);

  auto body = [&](int t, f32x4& Ar0, f32x4& Ar1) {
    // need: B(t) in LDS (all waves) + WAR-free buf for B(t+1).
    // outstanding (oldest->newest): [A(t) done-by-compiler-wait], B(t)(3),
    // A(t+1)(2)  ->  vmcnt(2) completes B(t), leaves A(t+1) flying.
    asm volatile("s_waitcnt vmcnt(2)" ::: "memory");
    __builtin_amdgcn_s_barrier();
    __builtin_amdgcn_sched_barrier(0);

    const int tn = (t + 1 < nch) ? (t + 1) : (nch - 1);      // clamp (uniform counts)
    stageB((t + 1) & 1, jb + tn * CHUNK);

    frag_cast Af[3];
    split8(Ar0, Ar1, Af);                                     // consumes A(t)
    const int tn2 = (t + 2 < nch) ? (t + 2) : (nch - 1);
    Ar0 = *(const f32x4*)(aA + (size_t)tn2 * CHUNK);          // issue A(t+2)
    Ar1 = *(const f32x4*)(aA + (size_t)tn2 * CHUNK + 4);

    const unsigned short* sBb = &sB[t & 1][0];
    f32x4 c[4];
#pragma unroll
    for (int nt = 0; nt < 4; ++nt) c[nt] = (f32x4){0.f, 0.f, 0.f, 0.f};

#pragma unroll
    for (int ng = 0; ng < 2; ++ng) {
      frag_cast Bv[2][3];
#pragma unroll
      for (int nn = 0; nn < 2; ++nn) {
        const int ncol = (ng * 2 + nn) * 16 + ln15;
        const int bq   = g ^ bkey;
#pragma unroll
        for (int lvl = 0; lvl < 3; ++lvl)
          Bv[nn][lvl].u = *(const u16x8*)(sBb + lvl * 2048 + ncol * 32 + bq * 8);
      }
#pragma unroll
      for (int term = 0; term < 6; ++term)
#pragma unroll
        for (int nn = 0; nn < 2; ++nn) {
          const int nt = ng * 2 + nn;
          c[nt] = __builtin_amdgcn_mfma_f32_16x16x32_bf16(
              Af[AI[term]].b, Bv[nn][BI[term]].b, c[nt], 0, 0, 0);
        }
    }
#pragma unroll
    for (int nt = 0; nt < 4; ++nt) {
      macc[nt][0] += (double)c[nt].x;
      macc[nt][1] += (double)c[nt].y;
      macc[nt][2] += (double)c[nt].z;
      macc[nt][3] += (double)c[nt].w;
    }
  };

#pragma unroll 1
  for (int t = 0; t < nch; t += 2) {
    body(t, Aa0, Aa1);
    body(t + 1, Ab0, Ab1);
  }

  // epilogue: D row = g*4 + r (within 16-tile), col = nt*16 + ln15
  if (DIRECT) {
#pragma unroll
    for (int nt = 0; nt < 4; ++nt)
#pragma unroll
      for (int r = 0; r < 4; ++r)
        outg[((size_t)b * NROW + i0 + wv * 16 + g * 4 + r) * NF + nt * 16 + ln15] =
            (macc[nt][r] > 0.5) ? 1.0f : 0.0f;
  } else {
    float* wb = wp + (size_t)z * TOT;
#pragma unroll
    for (int nt = 0; nt < 4; ++nt)
#pragma unroll
      for (int r = 0; r < 4; ++r)
        wb[((size_t)b * NROW + i0 + wv * 16 + g * 4 + r) * NF + nt * 16 + ln15] =
            (float)macc[nt][r];
  }
}

// ---- pass 3: reduce JSPLIT partials in f64, threshold ----
__global__ __launch_bounds__(256)
void combine_thresh(const float* __restrict__ wsv, float* __restrict__ outg) {
  const size_t e = ((size_t)blockIdx.x * 256 + threadIdx.x) * 4;
  f32x4 p0 = *(const f32x4*)(wsv + e);
  f32x4 p1 = *(const f32x4*)(wsv + e + TOT);
  f32x4 p2 = *(const f32x4*)(wsv + e + 2 * TOT);
  f32x4 p3 = *(const f32x4*)(wsv + e + 3 * TOT);
  f32x4 o;
  o.x = (((double)p0.x + p1.x + p2.x + p3.x) > 0.5) ? 1.0f : 0.0f;
  o.y = (((double)p0.y + p1.y + p2.y + p3.y) > 0.5) ? 1.0f : 0.0f;
  o.z = (((double)p0.z + p1.z + p2.z + p3.z) > 0.5) ? 1.0f : 0.0f;
  o.w = (((double)p0.w + p1.w + p2.w + p3.w) > 0.5) ? 1.0f : 0.0f;
  *(f32x4*)(outg + e) = o;
}

extern "C" void kernel_launch(void* const* d_in, const int* in_sizes, int n_in,
                              void* d_out, int out_size, void* d_ws, size_t ws_size,
                              hipStream_t stream) {
  const float* x = (const float*)d_in[0];
  const float* a = (const float*)d_in[1];
  float* out = (float*)d_out;
  unsigned short* xs = (unsigned short*)d_ws;                 // 6 MB
  float* wp = (float*)((char*)d_ws + 3 * TOT * sizeof(unsigned short));

  prep_x<<<dim3(NROW / 64, BATCH), dim3(256), 0, stream>>>(x, xs);

  const size_t need = 3 * TOT * sizeof(unsigned short)
                    + (size_t)JSPLIT * TOT * sizeof(float);   // 22 MB
  if (ws_size >= need) {
    gemm_mfma<false><<<dim3(JSPLIT * BATCH * (NROW / 64)), dim3(256), 0, stream>>>(
        a, xs, out, wp);
    combine_thresh<<<dim3((unsigned)(TOT / 1024)), dim3(256), 0, stream>>>(wp, out);
  } else {
    gemm_mfma<true><<<dim3(BATCH * (NROW / 64)), dim3(256), 0, stream>>>(
        a, xs, out, nullptr);
  }
}